// Round 3
// baseline (97.784 us; speedup 1.0000x reference)
//
#include <hip/hip_runtime.h>
#include <hip/hip_cooperative_groups.h>
#include <math.h>

namespace cg = cooperative_groups;

#define WL   140
#define OFC  118
#define TDN  21
#define COUT 10
#define KS   9
#define IW_SZ (OFC * OFC)       // 13924 floats

// ws layout (floats)
#define WS_ATT_A 0
#define WS_ATT_B 128
#define WS_FEATS 256

struct Params {
    const float *x;
    const float *tdA_in_w, *tdA_in_b, *tdA_out_w, *tdA_out_b;
    const float *tdB_in_w, *tdB_in_b, *tdB_out_w, *tdB_out_b;
    const float *cm_in_w, *cm_in_b, *cm_out_w, *cm_out_b;
    const float *projA_w, *projB_w, *conv_w, *conv_b;
    const float *fc1_w, *fc1_b, *fc2_w, *fc2_b;
    float *ws, *out;
};

struct TdSm {                    // blocks 0,1 (one full td side each)
    float w[IW_SZ];              // current weight matrix (q/k/v/out staged sequentially)
    float inp[TDN][120];         // wav sliding windows
    float eeg[16][OFC];
    float qp[16][OFC];
    float kp[TDN][OFC];
    float vp[TDN][OFC];
    float attn[16][TDN];
    float acs[TDN];
    float avcs[OFC];
    float colsum[OFC];
    float Ssum[16];
    float avsel[OFC];
    int   sel;
};

struct BrSm {                    // blocks 2..5 (one branch each)
    float arow[OFC];
    float pv[16];
    float eeg_s[16][OFC];
    float w_inT[16][48];
    float b_in[48];
    float tv[3][16];
    float w_out[16][16];
    float b_out[16];
    float cw[COUT * 16 * KS];
    float cb[COUT];
    float qpS[OFC][17];          // padded rows (bank-conflict-free q loads)
    float kpS[OFC][17];
    float vpS[OFC][17];
    float part_m[4][128];
    float part_l[4][128];
    float part_acc[4][OFC][17];
    float o2[OFC][17];
    float y[COUT][112];
};

union Sm { TdSm t; BrSm b; };    // ~104 KB < 160 KB LDS

// ---------------------------------------------------------------------------
__device__ void td_side(int b, int tid, const Params& p, TdSm& s)
{
    const float* in_w  = b ? p.tdB_in_w  : p.tdA_in_w;
    const float* in_b  = b ? p.tdB_in_b  : p.tdA_in_b;
    const float* out_w = b ? p.tdB_out_w : p.tdA_out_w;
    const float* out_b = b ? p.tdB_out_b : p.tdA_out_b;
    const float* wav   = p.x + (b ? 17 * WL : 0);

    // stage inputs (covered by the first post-weight-stage barrier)
    for (int e = tid; e < 16 * OFC; e += 512) {
        int r = e / OFC, c = e % OFC;
        s.eeg[r][c] = p.x[(1 + r) * WL + (WL - OFC) + c];
    }
    for (int e = tid; e < TDN * 120; e += 512) {
        int t = e / 120, j = e % 120;       // t+j <= 139 < 140
        s.inp[t][j] = wav[t + j];
    }

    const float scale_q = 1.0f / sqrtf((float)OFC);

    // ---- q/k/v projections, weight sections staged sequentially ----
    for (int sec = 0; sec < 3; ++sec) {
        __syncthreads();                    // previous users of s.w done
        const float4* wg = (const float4*)(in_w + sec * IW_SZ);
        float4* wd = (float4*)s.w;
        for (int e = tid; e < IW_SZ / 4; e += 512) wd[e] = wg[e];
        __syncthreads();

        const int   R     = (sec == 0) ? 16 : TDN;
        const float scale = (sec == 0) ? scale_q : 1.0f;
        float* dst = (sec == 0) ? &s.qp[0][0] : (sec == 1 ? &s.kp[0][0] : &s.vp[0][0]);

        for (int e = tid; e < R * 59; e += 512) {
            int r  = e / 59;
            int og = (e % 59) * 2;
            const float2* a  = (sec == 0) ? (const float2*)&s.eeg[r][0]
                                          : (const float2*)&s.inp[r][0];
            const float2* w0 = (const float2*)&s.w[og * OFC];
            const float2* w1 = (const float2*)&s.w[(og + 1) * OFC];
            float s0 = 0.f, s1 = 0.f;
            #pragma unroll 4
            for (int j = 0; j < 59; ++j) {
                float2 av = a[j], u = w0[j], v = w1[j];
                s0 += av.x * u.x + av.y * u.y;
                s1 += av.x * v.x + av.y * v.y;
            }
            dst[r * OFC + og]     = (s0 + in_b[sec * OFC + og])     * scale;
            dst[r * OFC + og + 1] = (s1 + in_b[sec * OFC + og + 1]) * scale;
        }
    }
    __syncthreads();                        // v-compute done reading s.w

    // stage out_w (latency hidden under score compute)
    {
        const float4* wg = (const float4*)out_w;
        float4* wd = (float4*)s.w;
        for (int e = tid; e < IW_SZ / 4; e += 512) wd[e] = wg[e];
    }
    // scores 16x21 (dot-118)
    if (tid < 16 * TDN) {
        int i = tid / TDN, t = tid % TDN;
        const float2* a  = (const float2*)&s.qp[i][0];
        const float2* k2 = (const float2*)&s.kp[t][0];
        float sc = 0.f;
        #pragma unroll 4
        for (int j = 0; j < 59; ++j) {
            float2 u = a[j], v = k2[j];
            sc += u.x * v.x + u.y * v.y;
        }
        s.attn[i][t] = sc;
    }
    __syncthreads();

    // softmax rows
    if (tid < 16) {
        float m = s.attn[tid][0];
        for (int t = 1; t < TDN; ++t) m = fmaxf(m, s.attn[tid][t]);
        float l = 0.f;
        for (int t = 0; t < TDN; ++t) {
            float pp = __expf(s.attn[tid][t] - m);
            s.attn[tid][t] = pp;
            l += pp;
        }
        float inv = 1.f / l;
        for (int t = 0; t < TDN; ++t) s.attn[tid][t] *= inv;
    }
    __syncthreads();

    if (tid < TDN) {
        float a = 0.f;
        for (int i = 0; i < 16; ++i) a += s.attn[i][tid];
        s.acs[tid] = a;
    }
    __syncthreads();

    if (tid < OFC) {
        float a = 0.f;
        for (int t = 0; t < TDN; ++t) a += s.acs[t] * s.vp[t][tid];
        s.avcs[tid] = a;
    }
    __syncthreads();

    // colsum[j] = avcs . out_w[j] + 16*b[j]
    if (tid < OFC) {
        const float2* a  = (const float2*)&s.avcs[0];
        const float2* w2 = (const float2*)&s.w[tid * OFC];
        float a0 = 0.f;
        #pragma unroll 4
        for (int j = 0; j < 59; ++j) {
            float2 u = a[j], v = w2[j];
            a0 += u.x * v.x + u.y * v.y;
        }
        s.colsum[tid] = a0 + 16.f * out_b[tid];
    }
    __syncthreads();

    if (tid < 16) {
        const float2* a = (const float2*)&s.eeg[tid][0];
        const float2* c = (const float2*)&s.colsum[0];
        float a0 = 0.f;
        for (int j = 0; j < 59; ++j) {
            float2 u = a[j], v = c[j];
            a0 += u.x * v.x + u.y * v.y;
        }
        s.Ssum[tid] = a0;
    }
    __syncthreads();

    if (tid == 0) {
        int best = 0; float bv = s.Ssum[0];
        for (int i = 1; i < 16; ++i)
            if (s.Ssum[i] > bv) { bv = s.Ssum[i]; best = i; }   // first-max
        s.sel = best;
    }
    __syncthreads();

    if (tid < OFC) {
        float a = 0.f;
        for (int t = 0; t < TDN; ++t) a += s.attn[s.sel][t] * s.vp[t][tid];
        s.avsel[tid] = a;
    }
    __syncthreads();

    if (tid < OFC) {
        const float2* a  = (const float2*)&s.avsel[0];
        const float2* w2 = (const float2*)&s.w[tid * OFC];
        float a0 = 0.f;
        #pragma unroll 4
        for (int j = 0; j < 59; ++j) {
            float2 u = a[j], v = w2[j];
            a0 += u.x * v.x + u.y * v.y;
        }
        p.ws[(b ? WS_ATT_B : WS_ATT_A) + tid] = a0 + out_b[tid];
    }
    __threadfence();
}

// ---------------------------------------------------------------------------
__device__ void br_pre(int br, int tid, const Params& p, BrSm& s)
{
    for (int e = tid; e < 16 * OFC; e += 512) {
        int r = e / OFC, c = e % OFC;
        s.eeg_s[r][c] = p.x[(1 + r) * WL + (WL - OFC) + c];
    }
    for (int e = tid; e < 768; e += 512) {
        int q = e / 16, r = e % 16;
        s.w_inT[r][q] = p.cm_in_w[br * 768 + e];
    }
    if (tid < 48) s.b_in[tid] = p.cm_in_b[br * 48 + tid];
    if (tid >= 64 && tid < 320) {
        int e = tid - 64;
        s.w_out[e >> 4][e & 15] = p.cm_out_w[br * 256 + e];
    }
    if (tid >= 384 && tid < 400) s.b_out[tid - 384] = p.cm_out_b[br * 16 + (tid - 384)];
    for (int e = tid; e < COUT * 16 * KS; e += 512) s.cw[e] = p.conv_w[br * 1440 + e];
    if (tid >= 400 && tid < 400 + COUT) s.cb[tid - 400] = p.conv_b[br * COUT + (tid - 400)];
    {
        const float* pvg = (br < 2) ? p.projA_w : p.projB_w;
        if (tid >= 416 && tid < 432) s.pv[tid - 416] = pvg[tid - 416];
    }
    __syncthreads();

    if (tid < 48) {
        float a = 0.f;
        #pragma unroll
        for (int r = 0; r < 16; ++r) a += s.pv[r] * s.w_inT[r][tid];
        s.tv[tid / 16][tid % 16] = a;
    }
    __syncthreads();

    // eeg-side q/k/v sections (don't depend on the selected rows)
    const bool d_r1 = (br == 0 || br == 3);      // data is rank-1 (wA/wB)
    for (int e = tid; e < 3 * OFC * 16; e += 512) {
        int sec = e / (OFC * 16);
        int rem = e - sec * OFC * 16;
        int j = rem >> 4, o = rem & 15;
        bool r1 = (sec == 0) ? d_r1 : !d_r1;
        if (!r1) {
            float a = 0.f;
            #pragma unroll
            for (int r = 0; r < 16; ++r) a += s.eeg_s[r][j] * s.w_inT[r][sec * 16 + o];
            a += s.b_in[sec * 16 + o];
            if (sec == 0) a *= 0.25f;
            float* dst = (sec == 0) ? &s.qpS[0][0] : (sec == 1 ? &s.kpS[0][0] : &s.vpS[0][0]);
            dst[j * 17 + o] = a;
        }
    }
}

// ---------------------------------------------------------------------------
__device__ void br_main(int br, int tid, const Params& p, BrSm& s)
{
    const bool d_r1 = (br == 0 || br == 3);
    const float* ar = p.ws + ((br < 2) ? WS_ATT_A : WS_ATT_B);
    for (int j = tid; j < OFC; j += 512) s.arow[j] = ar[j];
    __syncthreads();

    // rank-1 q/k/v sections (need arow)
    for (int e = tid; e < 3 * OFC * 16; e += 512) {
        int sec = e / (OFC * 16);
        int rem = e - sec * OFC * 16;
        int j = rem >> 4, o = rem & 15;
        bool r1 = (sec == 0) ? d_r1 : !d_r1;
        if (r1) {
            float a = s.tv[sec][o] * s.arow[j] + s.b_in[sec * 16 + o];
            if (sec == 0) a *= 0.25f;
            float* dst = (sec == 0) ? &s.qpS[0][0] : (sec == 1 ? &s.kpS[0][0] : &s.vpS[0][0]);
            dst[j * 17 + o] = a;
        }
    }
    __syncthreads();

    // flash attention over 118 kv, 4 slices
    const int g = tid >> 7, j = tid & 127;
    float q[16], acc[16];
    float m = -INFINITY, l = 0.f;
    #pragma unroll
    for (int r = 0; r < 16; ++r) acc[r] = 0.f;

    if (j < OFC) {
        #pragma unroll
        for (int r = 0; r < 16; ++r) q[r] = s.qpS[j][r];
        const int t0 = (g * OFC) >> 2, t1 = ((g + 1) * OFC) >> 2;
        for (int t = t0; t < t1; ++t) {
            const float* kr = &s.kpS[t][0];
            float sc = 0.f;
            #pragma unroll
            for (int r = 0; r < 16; ++r) sc += q[r] * kr[r];
            float mn = fmaxf(m, sc);
            float c  = __expf(m - mn);
            float pp = __expf(sc - mn);
            l = l * c + pp;
            const float* vr = &s.vpS[t][0];
            #pragma unroll
            for (int r = 0; r < 16; ++r) acc[r] = acc[r] * c + pp * vr[r];
            m = mn;
        }
        s.part_m[g][j] = m;
        s.part_l[g][j] = l;
        #pragma unroll
        for (int r = 0; r < 16; ++r) s.part_acc[g][j][r] = acc[r];
    }
    __syncthreads();

    // merge 4 slices + out-projection
    if (tid < OFC) {
        float m0 = s.part_m[0][tid], m1 = s.part_m[1][tid];
        float m2 = s.part_m[2][tid], m3 = s.part_m[3][tid];
        float mm = fmaxf(fmaxf(m0, m1), fmaxf(m2, m3));
        float c0 = __expf(m0 - mm), c1 = __expf(m1 - mm);
        float c2 = __expf(m2 - mm), c3 = __expf(m3 - mm);
        float ll = c0 * s.part_l[0][tid] + c1 * s.part_l[1][tid]
                 + c2 * s.part_l[2][tid] + c3 * s.part_l[3][tid];
        float inv = 1.f / ll;
        float orow[16];
        #pragma unroll
        for (int r = 0; r < 16; ++r)
            orow[r] = (c0 * s.part_acc[0][tid][r] + c1 * s.part_acc[1][tid][r]
                     + c2 * s.part_acc[2][tid][r] + c3 * s.part_acc[3][tid][r]) * inv;
        for (int c = 0; c < 16; ++c) {
            float a = s.b_out[c];
            #pragma unroll
            for (int d = 0; d < 16; ++d) a += orow[d] * s.w_out[c][d];
            s.o2[tid][c] = a;
        }
    }
    __syncthreads();

    // conv VALID + relu
    for (int e = tid; e < COUT * 110; e += 512) {
        int c = e / 110, pp = e % 110;
        float a = s.cb[c];
        for (int mI = 0; mI < 16; ++mI) {
            #pragma unroll
            for (int k = 0; k < KS; ++k)
                a += s.o2[pp + k][mI] * s.cw[(c * 16 + mI) * KS + k];
        }
        s.y[c][pp] = fmaxf(a, 0.f);
    }
    __syncthreads();

    if (tid < COUT) {
        float mx = s.y[tid][0];
        for (int pp = 1; pp < 110; ++pp) mx = fmaxf(mx, s.y[tid][pp]);
        p.ws[WS_FEATS + br * COUT + tid] = mx;
    }
    __threadfence();
}

// ---------------------------------------------------------------------------
__global__ __launch_bounds__(512) void fused_net(Params p)
{
    __shared__ Sm sm;
    cg::grid_group grid = cg::this_grid();
    const int blk = blockIdx.x;
    const int tid = threadIdx.x;

    if (blk < 2) td_side(blk, tid, p, sm.t);
    else         br_pre(blk - 2, tid, p, sm.b);

    grid.sync();

    if (blk >= 2) br_main(blk - 2, tid, p, sm.b);

    grid.sync();

    if (blk == 0) {
        float* fb = (float*)&sm;            // reuse LDS
        __syncthreads();
        if (tid < 40) fb[tid] = p.ws[WS_FEATS + tid];
        __syncthreads();
        if (tid < 40) {
            float a = p.fc1_b[tid];
            for (int k = 0; k < 40; ++k) a += fb[k] * p.fc1_w[tid * 40 + k];
            fb[64 + tid] = 1.f / (1.f + __expf(-a));
        }
        __syncthreads();
        if (tid < 2) {
            float a = p.fc2_b[tid];
            for (int k = 0; k < 40; ++k) a += fb[64 + k] * p.fc2_w[tid * 40 + k];
            p.out[tid] = 1.f / (1.f + __expf(-a));
        }
    }
}

// ---------------------------------------------------------------------------
extern "C" void kernel_launch(void* const* d_in, const int* in_sizes, int n_in,
                              void* d_out, int out_size, void* d_ws, size_t ws_size,
                              hipStream_t stream) {
    Params prm;
    prm.x         = (const float*)d_in[0];
    prm.tdA_in_w  = (const float*)d_in[1];
    prm.tdA_in_b  = (const float*)d_in[2];
    prm.tdA_out_w = (const float*)d_in[3];
    prm.tdA_out_b = (const float*)d_in[4];
    prm.tdB_in_w  = (const float*)d_in[5];
    prm.tdB_in_b  = (const float*)d_in[6];
    prm.tdB_out_w = (const float*)d_in[7];
    prm.tdB_out_b = (const float*)d_in[8];
    prm.cm_in_w   = (const float*)d_in[9];
    prm.cm_in_b   = (const float*)d_in[10];
    prm.cm_out_w  = (const float*)d_in[11];
    prm.cm_out_b  = (const float*)d_in[12];
    prm.projA_w   = (const float*)d_in[13];
    prm.projB_w   = (const float*)d_in[14];
    prm.conv_w    = (const float*)d_in[15];
    prm.conv_b    = (const float*)d_in[16];
    prm.fc1_w     = (const float*)d_in[17];
    prm.fc1_b     = (const float*)d_in[18];
    prm.fc2_w     = (const float*)d_in[19];
    prm.fc2_b     = (const float*)d_in[20];
    prm.ws        = (float*)d_ws;
    prm.out       = (float*)d_out;

    void* args[] = { &prm };
    hipLaunchCooperativeKernel((const void*)fused_net, dim3(6), dim3(512),
                               args, 0, stream);
}